// Round 10
// baseline (3751.502 us; speedup 1.0000x reference)
//
#include <hip/hip_runtime.h>
#include <math.h>

#define B_ 32
#define N_ 16384
#define K_ 64
#define D_ 256
#define NUM_ITERS_ 20

#define F2 (20.0f * 1.4426950408889634f)   // (1/eps)*log2(e)
#define CLAMP2 (-144.26950408889634f)      // -100*log2(e)
#define NUW 0.015625f                      // 1/64

typedef __attribute__((ext_vector_type(8))) short short8;
typedef _Float16 half8 __attribute__((ext_vector_type(8)));
typedef __attribute__((ext_vector_type(4))) float f32x4;

__device__ __forceinline__ float exp2fast(float x) {
#if __has_builtin(__builtin_amdgcn_exp2f)
  return __builtin_amdgcn_exp2f(x);
#else
  return __expf(x * 0.6931471805599453f);
#endif
}

__device__ __forceinline__ unsigned short cvt_bf16_rne(float x) {
  unsigned u = __float_as_uint(x);
  unsigned r = u + 0x7fffu + ((u >> 16) & 1u);
  return (unsigned short)(r >> 16);
}

__device__ __forceinline__ float cvt_lo(unsigned u) {
  unsigned short h = (unsigned short)(u & 0xffffu);
  _Float16 f;
  __builtin_memcpy(&f, &h, 2);
  return (float)f;
}
__device__ __forceinline__ float cvt_hi(unsigned u) {
  unsigned short h = (unsigned short)(u >> 16);
  _Float16 f;
  __builtin_memcpy(&f, &h, 2);
  return (float)f;
}

// ---------- slot prep: fp32 -> bf16 hi/lo planes + exact fp32 ssq ----------
__global__ __launch_bounds__(64) void slot_prep_kernel(
    const float* __restrict__ slot, unsigned short* __restrict__ bhi,
    unsigned short* __restrict__ blo, float* __restrict__ ssq)
{
  const int bk = blockIdx.x;
  const int t  = threadIdx.x;
  const size_t base = (size_t)bk * D_ + t * 4;
  float4 v = *(const float4*)(slot + base);
  float x[4] = {v.x, v.y, v.z, v.w};
  unsigned short h[4], lo[4];
  float sq = 0.f;
#pragma unroll
  for (int i = 0; i < 4; ++i) {
    sq = fmaf(x[i], x[i], sq);
    h[i] = cvt_bf16_rne(x[i]);
    float hf = __uint_as_float((unsigned)h[i] << 16);
    lo[i] = cvt_bf16_rne(x[i] - hf);
  }
  *(ushort4*)(bhi + base) = make_ushort4(h[0], h[1], h[2], h[3]);
  *(ushort4*)(blo + base) = make_ushort4(lo[0], lo[1], lo[2], lo[3]);
#pragma unroll
  for (int off = 32; off >= 1; off >>= 1) sq += __shfl_xor(sq, off);
  if (t == 0) ssq[bk] = sq;
}

// ---------- Phase 1: E = 2^(log2K - rowmax) (fp16) + fused iteration 1 ----------
__global__ __launch_bounds__(256) void logk_mfma_kernel(
    const float* __restrict__ pix, const unsigned short* __restrict__ bhi,
    const unsigned short* __restrict__ blo, const float* __restrict__ ssq,
    const float* __restrict__ sw, _Float16* __restrict__ E,
    float* __restrict__ Tp)
{
  __shared__ unsigned short Bl[2][K_][D_];   // 64 KB; reused as fp16 transpose scratch
  __shared__ float psq_s[256];               // psq, then row sums s
  __shared__ float ssq_s[K_];
  __shared__ float wm_l[4][K_];
  __shared__ float W_l[256];

  const int t  = threadIdx.x;
  const int w  = t >> 6;
  const int l  = t & 63;
  const int lr = l & 15;
  const int lk = l >> 4;
  const int b  = blockIdx.y;
  const int n0 = blockIdx.x * 256;

  {
    const unsigned short* pl0 = bhi + (size_t)b * K_ * D_;
    const unsigned short* pl1 = blo + (size_t)b * K_ * D_;
#pragma unroll
    for (int i = 0; i < 16; ++i) {
      int ci = i * 256 + t;
      int plane = ci >> 11;
      int k = (ci >> 5) & 63;
      int c = (ci & 31) << 4;
      int srcb = c ^ ((k & 7) << 4);
      const unsigned short* sp = (plane ? pl1 : pl0) + (size_t)k * D_ + (srcb >> 1);
      short8 vv = *(const short8*)sp;
      *(short8*)((char*)(&Bl[plane][k][0]) + c) = vv;
    }
    if (t < K_) ssq_s[t] = ssq[b * K_ + t];
  }

  const float* pg = pix + ((size_t)b * N_ + n0 + w * 64 + lr) * D_ + lk * 8;

  f32x4 acc[4][4];
#pragma unroll
  for (int i = 0; i < 4; ++i)
#pragma unroll
    for (int j = 0; j < 4; ++j) acc[i][j] = (f32x4){0.f, 0.f, 0.f, 0.f};
  float psq[4] = {0.f, 0.f, 0.f, 0.f};

  float4 st[4][2];
#pragma unroll
  for (int rg = 0; rg < 4; ++rg) {
    st[rg][0] = *(const float4*)(pg + (size_t)rg * 16 * D_);
    st[rg][1] = *(const float4*)(pg + (size_t)rg * 16 * D_ + 4);
  }
  __syncthreads();

  for (int s = 0; s < 8; ++s) {
    short8 ahi[4], alo[4];
#pragma unroll
    for (int rg = 0; rg < 4; ++rg) {
      float xs[8];
      *(float4*)&xs[0] = st[rg][0];
      *(float4*)&xs[4] = st[rg][1];
#pragma unroll
      for (int j = 0; j < 8; ++j) {
        float x = xs[j];
        psq[rg] = fmaf(x, x, psq[rg]);
        unsigned short h = cvt_bf16_rne(x);
        ahi[rg][j] = (short)h;
        float hf = __uint_as_float((unsigned)h << 16);
        alo[rg][j] = (short)cvt_bf16_rne(x - hf);
      }
    }
    if (s < 7) {
#pragma unroll
      for (int rg = 0; rg < 4; ++rg) {
        st[rg][0] = *(const float4*)(pg + (size_t)rg * 16 * D_ + (s + 1) * 32);
        st[rg][1] = *(const float4*)(pg + (size_t)rg * 16 * D_ + (s + 1) * 32 + 4);
      }
    }
    short8 bh[4], bl[4];
    const int dbyte = s * 64 + lk * 16;
#pragma unroll
    for (int cg = 0; cg < 4; ++cg) {
      int krow = cg * 16 + lr;
      int off = dbyte ^ ((krow & 7) << 4);
      bh[cg] = *(const short8*)((const char*)(&Bl[0][krow][0]) + off);
      bl[cg] = *(const short8*)((const char*)(&Bl[1][krow][0]) + off);
    }
#pragma unroll
    for (int rg = 0; rg < 4; ++rg)
#pragma unroll
      for (int cg = 0; cg < 4; ++cg) {
        acc[rg][cg] = __builtin_amdgcn_mfma_f32_16x16x32_bf16(ahi[rg], bh[cg], acc[rg][cg], 0, 0, 0);
        acc[rg][cg] = __builtin_amdgcn_mfma_f32_16x16x32_bf16(ahi[rg], bl[cg], acc[rg][cg], 0, 0, 0);
        acc[rg][cg] = __builtin_amdgcn_mfma_f32_16x16x32_bf16(alo[rg], bh[cg], acc[rg][cg], 0, 0, 0);
      }
  }

#pragma unroll
  for (int rg = 0; rg < 4; ++rg) {
    psq[rg] += __shfl_xor(psq[rg], 16);
    psq[rg] += __shfl_xor(psq[rg], 32);
  }
  if (l < 16) {
#pragma unroll
    for (int rg = 0; rg < 4; ++rg) psq_s[w * 64 + rg * 16 + lr] = psq[rg];
  }
  __syncthreads();   // psq_s ready; all waves done reading Bl (scr reuse safe)

  float mss[4];
#pragma unroll
  for (int cg = 0; cg < 4; ++cg) mss[cg] = ssq_s[cg * 16 + lr];

  // log2_K into acc
#pragma unroll
  for (int rg = 0; rg < 4; ++rg)
#pragma unroll
    for (int qq = 0; qq < 4; ++qq) {
      float ps_ = psq_s[w * 64 + rg * 16 + lk * 4 + qq];
#pragma unroll
      for (int cg = 0; cg < 4; ++cg) {
        float C = ps_ + mss[cg] - 2.f * acc[rg][cg][qq];
        acc[rg][cg][qq] = fmaxf(-F2 * C, CLAMP2);
      }
    }

  // per-row max -> E = 2^(lk - rmax); row sums s (= iter-1 row pass with V=1)
#pragma unroll
  for (int rg = 0; rg < 4; ++rg)
#pragma unroll
    for (int qq = 0; qq < 4; ++qq) {
      float m = fmaxf(fmaxf(acc[rg][0][qq], acc[rg][1][qq]),
                      fmaxf(acc[rg][2][qq], acc[rg][3][qq]));
      m = fmaxf(m, __shfl_xor(m, 1));
      m = fmaxf(m, __shfl_xor(m, 2));
      m = fmaxf(m, __shfl_xor(m, 4));
      m = fmaxf(m, __shfl_xor(m, 8));
#pragma unroll
      for (int cg = 0; cg < 4; ++cg)
        acc[rg][cg][qq] = exp2fast(acc[rg][cg][qq] - m);
      float s = acc[rg][0][qq] + acc[rg][1][qq] + acc[rg][2][qq] + acc[rg][3][qq];
      s += __shfl_xor(s, 1);
      s += __shfl_xor(s, 2);
      s += __shfl_xor(s, 4);
      s += __shfl_xor(s, 8);
      if (lr == 0) psq_s[w * 64 + rg * 16 + lk * 4 + qq] = s;  // own-wave segment
    }

  // W_n = max(sw,1e-8)/s_n  (row t of this block; same-wave LDS segment)
  {
    float sv = psq_s[t];
    float muw = fmaxf(sw[(size_t)b * N_ + n0 + t], 1e-8f);
    W_l[t] = muw / sv;
  }

  // iter-1 column partials: T_k = sum_n E_nk * W_n over this block's 256 rows
  float Wv[4][4];
#pragma unroll
  for (int rg = 0; rg < 4; ++rg)
#pragma unroll
    for (int qq = 0; qq < 4; ++qq)
      Wv[rg][qq] = W_l[w * 64 + rg * 16 + lk * 4 + qq];
#pragma unroll
  for (int cg = 0; cg < 4; ++cg) {
    float Tt = 0.f;
#pragma unroll
    for (int rg = 0; rg < 4; ++rg)
#pragma unroll
      for (int qq = 0; qq < 4; ++qq)
        Tt = fmaf(acc[rg][cg][qq], Wv[rg][qq], Tt);
    Tt += __shfl_xor(Tt, 16);
    Tt += __shfl_xor(Tt, 32);
    if (lk == 0) wm_l[w][cg * 16 + lr] = Tt;
  }

  // transpose-stage E (fp16) into LDS scratch (rows padded to 72 halves)
  _Float16* scr = (_Float16*)Bl + (size_t)w * 64 * 72;
#pragma unroll
  for (int rg = 0; rg < 4; ++rg)
#pragma unroll
    for (int cg = 0; cg < 4; ++cg)
#pragma unroll
      for (int qq = 0; qq < 4; ++qq)
        scr[(rg * 16 + lk * 4 + qq) * 72 + cg * 16 + lr] = (_Float16)acc[rg][cg][qq];
  __syncthreads();

  if (t < 64) {
    float T = wm_l[0][t] + wm_l[1][t] + wm_l[2][t] + wm_l[3][t];
    Tp[((size_t)b * 64 + blockIdx.x) * 64 + t] = T;
  }

  // coalesced flush of fp16 E tile
  _Float16* dst = E + ((size_t)b * N_ + n0 + w * 64) * 64;
#pragma unroll
  for (int f = 0; f < 8; ++f) {
    int u = f * 64 + l;
    int row = u >> 3, kq = u & 7;
    half8 v8 = *(const half8*)(scr + row * 72 + kq * 8);
    *(half8*)(dst + row * 64 + kq * 8) = v8;
  }
}

// ---------- persistent iterations 2..20: E pinned in registers ----------
// 1024 blocks (32/batch) x 256 threads x 2 rows/thread. Scalar arrays with
// fully-literal unrolled indices (SROA -> SSA); amdgpu_waves_per_eu(4,4)
// forces the 128-VGPR budget so E stays live across iterations (r9 lesson:
// default budget 64 made the allocator re-load E from global every iter).
__global__ __launch_bounds__(256)
__attribute__((amdgpu_waves_per_eu(4, 4)))
void iterp_kernel(
    const _Float16* __restrict__ E, const float* __restrict__ sw,
    const float* __restrict__ Tp64, float* __restrict__ Ta,
    float* __restrict__ Tb, float* __restrict__ W,
    int* __restrict__ bar)
{
  __shared__ float wT[4][64];
  __shared__ __align__(16) float V_s[64];

  const int t = threadIdx.x;
  const int w = t >> 6, l = t & 63;
  const int bid = blockIdx.x;
  const int b = bid >> 5;           // batch
  const int blk = bid & 31;         // block within batch
  const size_t rowg0 = (size_t)b * N_ + blk * 512 + t;
  const size_t rowg1 = rowg0 + 256;

  const float muw0 = fmaxf(sw[rowg0], 1e-8f);
  const float muw1 = fmaxf(sw[rowg1], 1e-8f);

  // E rows as plain scalars: e*[j] holds halves k=2j,2j+1 (ea: k<32, eb: k>=32)
  unsigned ea0[16], eb0[16], ea1[16], eb1[16];
  {
    const uint4* p0 = (const uint4*)(E + rowg0 * 64);
    const uint4* p1 = (const uint4*)(E + rowg1 * 64);
#pragma unroll
    for (int i = 0; i < 4; ++i) {
      uint4 v;
      v = p0[i];     ea0[4*i] = v.x; ea0[4*i+1] = v.y; ea0[4*i+2] = v.z; ea0[4*i+3] = v.w;
      v = p0[4 + i]; eb0[4*i] = v.x; eb0[4*i+1] = v.y; eb0[4*i+2] = v.z; eb0[4*i+3] = v.w;
      v = p1[i];     ea1[4*i] = v.x; ea1[4*i+1] = v.y; ea1[4*i+2] = v.z; ea1[4*i+3] = v.w;
      v = p1[4 + i]; eb1[4*i] = v.x; eb1[4*i+1] = v.y; eb1[4*i+2] = v.z; eb1[4*i+3] = v.w;
    }
  }

  float W0 = 0.f, W1 = 0.f;
  int* bcnt = bar + b * 32;   // 128 B apart per batch
  const bool up32 = (l & 32) != 0;
  const bool up16 = (l & 16) != 0;
  const bool up8  = (l & 8)  != 0;
  const bool up4  = (l & 4)  != 0;
  const bool up2  = (l & 2)  != 0;
  const bool up1  = (l & 1)  != 0;

  for (int it = 2; it <= NUM_ITERS_; ++it) {
    // merge previous column partials -> V
    {
      const float* ti;
      int ch;
      if (it == 2)      { ti = Tp64 + ((size_t)b * 64 + w * 16) * 64 + l; ch = 16; }
      else if (it & 1)  { ti = Ta   + ((size_t)b * 32 + w * 8)  * 64 + l; ch = 8;  }
      else              { ti = Tb   + ((size_t)b * 32 + w * 8)  * 64 + l; ch = 8;  }
      float tp = 0.f;
      for (int i = 0; i < ch; ++i) tp += ti[(size_t)i * 64];
      wT[w][l] = tp;
    }
    __syncthreads();
    if (t < 64) V_s[t] = NUW / (wT[0][t] + wT[1][t] + wT[2][t] + wT[3][t]);
    __syncthreads();

    // row pass: s = E_row . V
    float s0 = 0.f, s1 = 0.f;
#pragma unroll
    for (int j = 0; j < 16; ++j) {
      float2 va = *(const float2*)&V_s[2 * j];
      float2 vb = *(const float2*)&V_s[32 + 2 * j];
      s0 = fmaf(cvt_lo(ea0[j]), va.x, s0);
      s0 = fmaf(cvt_hi(ea0[j]), va.y, s0);
      s0 = fmaf(cvt_lo(eb0[j]), vb.x, s0);
      s0 = fmaf(cvt_hi(eb0[j]), vb.y, s0);
      s1 = fmaf(cvt_lo(ea1[j]), va.x, s1);
      s1 = fmaf(cvt_hi(ea1[j]), va.y, s1);
      s1 = fmaf(cvt_lo(eb1[j]), vb.x, s1);
      s1 = fmaf(cvt_hi(eb1[j]), vb.y, s1);
    }
    W0 = muw0 / s0;
    W1 = muw1 / s1;

    // col pass: 2-row products + butterfly transpose-reduce
    // (keep own-group half, send the other half; all indices literal)
    float cur[32];
#pragma unroll
    for (int i = 0; i < 16; ++i) {          // level 32 fused with products
      float lo0 = cvt_lo(ea0[i]) * W0 + cvt_lo(ea1[i]) * W1;   // k = 2i
      float lo1 = cvt_hi(ea0[i]) * W0 + cvt_hi(ea1[i]) * W1;   // k = 2i+1
      float hi0 = cvt_lo(eb0[i]) * W0 + cvt_lo(eb1[i]) * W1;   // k = 32+2i
      float hi1 = cvt_hi(eb0[i]) * W0 + cvt_hi(eb1[i]) * W1;   // k = 33+2i
      float k0 = up32 ? hi0 : lo0, sd0 = up32 ? lo0 : hi0;
      float k1 = up32 ? hi1 : lo1, sd1 = up32 ? lo1 : hi1;
      cur[2 * i]     = k0 + __shfl_xor(sd0, 32);
      cur[2 * i + 1] = k1 + __shfl_xor(sd1, 32);
    }
#pragma unroll
    for (int i = 0; i < 16; ++i) {          // level 16
      float a = cur[i], bv = cur[16 + i];
      float kp = up16 ? bv : a, sd = up16 ? a : bv;
      cur[i] = kp + __shfl_xor(sd, 16);
    }
#pragma unroll
    for (int i = 0; i < 8; ++i) {           // level 8
      float a = cur[i], bv = cur[8 + i];
      float kp = up8 ? bv : a, sd = up8 ? a : bv;
      cur[i] = kp + __shfl_xor(sd, 8);
    }
#pragma unroll
    for (int i = 0; i < 4; ++i) {           // level 4
      float a = cur[i], bv = cur[4 + i];
      float kp = up4 ? bv : a, sd = up4 ? a : bv;
      cur[i] = kp + __shfl_xor(sd, 4);
    }
#pragma unroll
    for (int i = 0; i < 2; ++i) {           // level 2
      float a = cur[i], bv = cur[2 + i];
      float kp = up2 ? bv : a, sd = up2 ? a : bv;
      cur[i] = kp + __shfl_xor(sd, 2);
    }
    {                                       // level 1
      float a = cur[0], bv = cur[1];
      float kp = up1 ? bv : a, sd = up1 ? a : bv;
      cur[0] = kp + __shfl_xor(sd, 1);
    }

    wT[w][l] = cur[0];
    __syncthreads();
    if (t < 64) {
      float* Tout = (it & 1) ? Tb : Ta;
      Tout[((size_t)b * 32 + blk) * 64 + t] =
          wT[0][t] + wT[1][t] + wT[2][t] + wT[3][t];
    }

    // per-batch generation barrier (skip after the last body)
    if (it < NUM_ITERS_) {
      __threadfence();
      __syncthreads();
      if (t == 0) {
        __hip_atomic_fetch_add(bcnt, 1, __ATOMIC_ACQ_REL,
                               __HIP_MEMORY_SCOPE_AGENT);
        const int target = 32 * (it - 1);
        while (__hip_atomic_load(bcnt, __ATOMIC_ACQUIRE,
                                 __HIP_MEMORY_SCOPE_AGENT) < target)
          __builtin_amdgcn_s_sleep(2);
      }
      __syncthreads();
    }
  }
  W[rowg0] = W0;
  W[rowg1] = W1;
}

// ---------- final column merge -> V ----------
__global__ __launch_bounds__(64) void col_merge_kernel(
    const float* __restrict__ Tin, float* __restrict__ Vf)
{
  const int b = blockIdx.x;
  const int k = threadIdx.x;
  float T = 0.f;
#pragma unroll
  for (int j = 0; j < 32; ++j) T += Tin[((size_t)b * 32 + j) * 64 + k];
  Vf[b * 64 + k] = NUW / T;
}

// ---------- finalize: P = W_n * E_nk * V_k ----------
__global__ __launch_bounds__(256) void finalize_kernel(
    const _Float16* __restrict__ E, const float* __restrict__ W,
    const float* __restrict__ Vf, float* __restrict__ out)
{
  const size_t tid = (size_t)blockIdx.x * 256 + threadIdx.x;
  const size_t e0 = tid * 8;
  const int k0 = (int)(e0 & 63);
  const size_t bn = e0 >> 6;
  const int b = (int)(bn >> 14);
  const float Wv = W[bn];
  half8 ev = *(const half8*)(E + e0);
  float4 v0 = *(const float4*)(Vf + b * 64 + k0);
  float4 v1 = *(const float4*)(Vf + b * 64 + k0 + 4);
  float4 o0, o1;
  o0.x = Wv * (float)ev[0] * v0.x;
  o0.y = Wv * (float)ev[1] * v0.y;
  o0.z = Wv * (float)ev[2] * v0.z;
  o0.w = Wv * (float)ev[3] * v0.w;
  o1.x = Wv * (float)ev[4] * v1.x;
  o1.y = Wv * (float)ev[5] * v1.y;
  o1.z = Wv * (float)ev[6] * v1.z;
  o1.w = Wv * (float)ev[7] * v1.w;
  *(float4*)(out + e0) = o0;
  *(float4*)(out + e0 + 4) = o1;
}

extern "C" void kernel_launch(void* const* d_in, const int* in_sizes, int n_in,
                              void* d_out, int out_size, void* d_ws, size_t ws_size,
                              hipStream_t stream)
{
  const float* pix  = (const float*)d_in[0];
  const float* slot = (const float*)d_in[1];
  const float* sw   = (const float*)d_in[2];
  float* out = (float*)d_out;

  char* ws = (char*)d_ws;
  float* W    = (float*)ws;                              // 2 MB
  float* Vf   = (float*)(ws + (2ull << 20));             // 8 KB
  float* ssq  = (float*)(ws + (2ull << 20) + 65536);     // 8 KB
  int*   bar  = (int*)  (ws + (2ull << 20) + 131072);    // 4 KB
  float* TpA  = (float*)(ws + (3ull << 20));             // 512 KB (64 partials/batch)
  float* Ta   = (float*)(ws + (4ull << 20));             // 256 KB (32 partials/batch)
  float* Tb   = (float*)(ws + (5ull << 20));             // 256 KB
  unsigned short* bhi = (unsigned short*)(ws + (6ull << 20));  // 1 MB
  unsigned short* blo = (unsigned short*)(ws + (7ull << 20));  // 1 MB
  _Float16* E = (_Float16*)(ws + (8ull << 20));          // 67 MB

  hipMemsetAsync(bar, 0, 4096, stream);
  slot_prep_kernel<<<B_ * K_, 64, 0, stream>>>(slot, bhi, blo, ssq);
  logk_mfma_kernel<<<dim3(N_ / 256, B_), 256, 0, stream>>>(
      pix, bhi, blo, ssq, sw, E, TpA);
  iterp_kernel<<<dim3(1024), 256, 0, stream>>>(E, sw, TpA, Ta, Tb, W, bar);
  col_merge_kernel<<<B_, 64, 0, stream>>>(Ta, Vf);
  finalize_kernel<<<(unsigned)(((size_t)B_ * N_ * K_ / 8) / 256), 256, 0, stream>>>(
      E, W, Vf, out);
}

// Round 11
// 2856.204 us; speedup vs baseline: 1.3135x; 1.3135x over previous
//
#include <hip/hip_runtime.h>
#include <math.h>

#define B_ 32
#define N_ 16384
#define K_ 64
#define D_ 256
#define NUM_ITERS_ 20

#define F2 (20.0f * 1.4426950408889634f)   // (1/eps)*log2(e)
#define CLAMP2 (-144.26950408889634f)      // -100*log2(e)
#define NUW 0.015625f                      // 1/64
#define EROWS_LDS 488

typedef __attribute__((ext_vector_type(8))) short short8;
typedef _Float16 half8 __attribute__((ext_vector_type(8)));
typedef __attribute__((ext_vector_type(4))) float f32x4;

__device__ __forceinline__ float exp2fast(float x) {
#if __has_builtin(__builtin_amdgcn_exp2f)
  return __builtin_amdgcn_exp2f(x);
#else
  return __expf(x * 0.6931471805599453f);
#endif
}

__device__ __forceinline__ unsigned short cvt_bf16_rne(float x) {
  unsigned u = __float_as_uint(x);
  unsigned r = u + 0x7fffu + ((u >> 16) & 1u);
  return (unsigned short)(r >> 16);
}

__device__ __forceinline__ float cvt_lo(unsigned u) {
  unsigned short h = (unsigned short)(u & 0xffffu);
  _Float16 f;
  __builtin_memcpy(&f, &h, 2);
  return (float)f;
}
__device__ __forceinline__ float cvt_hi(unsigned u) {
  unsigned short h = (unsigned short)(u >> 16);
  _Float16 f;
  __builtin_memcpy(&f, &h, 2);
  return (float)f;
}

// ---------- slot prep: fp32 -> bf16 hi/lo planes + exact fp32 ssq ----------
__global__ __launch_bounds__(64) void slot_prep_kernel(
    const float* __restrict__ slot, unsigned short* __restrict__ bhi,
    unsigned short* __restrict__ blo, float* __restrict__ ssq)
{
  const int bk = blockIdx.x;
  const int t  = threadIdx.x;
  const size_t base = (size_t)bk * D_ + t * 4;
  float4 v = *(const float4*)(slot + base);
  float x[4] = {v.x, v.y, v.z, v.w};
  unsigned short h[4], lo[4];
  float sq = 0.f;
#pragma unroll
  for (int i = 0; i < 4; ++i) {
    sq = fmaf(x[i], x[i], sq);
    h[i] = cvt_bf16_rne(x[i]);
    float hf = __uint_as_float((unsigned)h[i] << 16);
    lo[i] = cvt_bf16_rne(x[i] - hf);
  }
  *(ushort4*)(bhi + base) = make_ushort4(h[0], h[1], h[2], h[3]);
  *(ushort4*)(blo + base) = make_ushort4(lo[0], lo[1], lo[2], lo[3]);
#pragma unroll
  for (int off = 32; off >= 1; off >>= 1) sq += __shfl_xor(sq, off);
  if (t == 0) ssq[bk] = sq;
}

// ---------- Phase 1: E = 2^(log2K - rowmax) (fp16) + fused iteration 1 ----------
__global__ __launch_bounds__(256) void logk_mfma_kernel(
    const float* __restrict__ pix, const unsigned short* __restrict__ bhi,
    const unsigned short* __restrict__ blo, const float* __restrict__ ssq,
    const float* __restrict__ sw, _Float16* __restrict__ E,
    float* __restrict__ Tp)
{
  __shared__ unsigned short Bl[2][K_][D_];   // 64 KB; reused as fp16 transpose scratch
  __shared__ float psq_s[256];               // psq, then row sums s
  __shared__ float ssq_s[K_];
  __shared__ float wm_l[4][K_];
  __shared__ float W_l[256];

  const int t  = threadIdx.x;
  const int w  = t >> 6;
  const int l  = t & 63;
  const int lr = l & 15;
  const int lk = l >> 4;
  const int b  = blockIdx.y;
  const int n0 = blockIdx.x * 256;

  {
    const unsigned short* pl0 = bhi + (size_t)b * K_ * D_;
    const unsigned short* pl1 = blo + (size_t)b * K_ * D_;
#pragma unroll
    for (int i = 0; i < 16; ++i) {
      int ci = i * 256 + t;
      int plane = ci >> 11;
      int k = (ci >> 5) & 63;
      int c = (ci & 31) << 4;
      int srcb = c ^ ((k & 7) << 4);
      const unsigned short* sp = (plane ? pl1 : pl0) + (size_t)k * D_ + (srcb >> 1);
      short8 vv = *(const short8*)sp;
      *(short8*)((char*)(&Bl[plane][k][0]) + c) = vv;
    }
    if (t < K_) ssq_s[t] = ssq[b * K_ + t];
  }

  const float* pg = pix + ((size_t)b * N_ + n0 + w * 64 + lr) * D_ + lk * 8;

  f32x4 acc[4][4];
#pragma unroll
  for (int i = 0; i < 4; ++i)
#pragma unroll
    for (int j = 0; j < 4; ++j) acc[i][j] = (f32x4){0.f, 0.f, 0.f, 0.f};
  float psq[4] = {0.f, 0.f, 0.f, 0.f};

  float4 st[4][2];
#pragma unroll
  for (int rg = 0; rg < 4; ++rg) {
    st[rg][0] = *(const float4*)(pg + (size_t)rg * 16 * D_);
    st[rg][1] = *(const float4*)(pg + (size_t)rg * 16 * D_ + 4);
  }
  __syncthreads();

  for (int s = 0; s < 8; ++s) {
    short8 ahi[4], alo[4];
#pragma unroll
    for (int rg = 0; rg < 4; ++rg) {
      float xs[8];
      *(float4*)&xs[0] = st[rg][0];
      *(float4*)&xs[4] = st[rg][1];
#pragma unroll
      for (int j = 0; j < 8; ++j) {
        float x = xs[j];
        psq[rg] = fmaf(x, x, psq[rg]);
        unsigned short h = cvt_bf16_rne(x);
        ahi[rg][j] = (short)h;
        float hf = __uint_as_float((unsigned)h << 16);
        alo[rg][j] = (short)cvt_bf16_rne(x - hf);
      }
    }
    if (s < 7) {
#pragma unroll
      for (int rg = 0; rg < 4; ++rg) {
        st[rg][0] = *(const float4*)(pg + (size_t)rg * 16 * D_ + (s + 1) * 32);
        st[rg][1] = *(const float4*)(pg + (size_t)rg * 16 * D_ + (s + 1) * 32 + 4);
      }
    }
    short8 bh[4], bl[4];
    const int dbyte = s * 64 + lk * 16;
#pragma unroll
    for (int cg = 0; cg < 4; ++cg) {
      int krow = cg * 16 + lr;
      int off = dbyte ^ ((krow & 7) << 4);
      bh[cg] = *(const short8*)((const char*)(&Bl[0][krow][0]) + off);
      bl[cg] = *(const short8*)((const char*)(&Bl[1][krow][0]) + off);
    }
#pragma unroll
    for (int rg = 0; rg < 4; ++rg)
#pragma unroll
      for (int cg = 0; cg < 4; ++cg) {
        acc[rg][cg] = __builtin_amdgcn_mfma_f32_16x16x32_bf16(ahi[rg], bh[cg], acc[rg][cg], 0, 0, 0);
        acc[rg][cg] = __builtin_amdgcn_mfma_f32_16x16x32_bf16(ahi[rg], bl[cg], acc[rg][cg], 0, 0, 0);
        acc[rg][cg] = __builtin_amdgcn_mfma_f32_16x16x32_bf16(alo[rg], bh[cg], acc[rg][cg], 0, 0, 0);
      }
  }

#pragma unroll
  for (int rg = 0; rg < 4; ++rg) {
    psq[rg] += __shfl_xor(psq[rg], 16);
    psq[rg] += __shfl_xor(psq[rg], 32);
  }
  if (l < 16) {
#pragma unroll
    for (int rg = 0; rg < 4; ++rg) psq_s[w * 64 + rg * 16 + lr] = psq[rg];
  }
  __syncthreads();   // psq_s ready; all waves done reading Bl (scr reuse safe)

  float mss[4];
#pragma unroll
  for (int cg = 0; cg < 4; ++cg) mss[cg] = ssq_s[cg * 16 + lr];

  // log2_K into acc
#pragma unroll
  for (int rg = 0; rg < 4; ++rg)
#pragma unroll
    for (int qq = 0; qq < 4; ++qq) {
      float ps_ = psq_s[w * 64 + rg * 16 + lk * 4 + qq];
#pragma unroll
      for (int cg = 0; cg < 4; ++cg) {
        float C = ps_ + mss[cg] - 2.f * acc[rg][cg][qq];
        acc[rg][cg][qq] = fmaxf(-F2 * C, CLAMP2);
      }
    }

  // per-row max -> E = 2^(lk - rmax); row sums s (= iter-1 row pass with V=1)
#pragma unroll
  for (int rg = 0; rg < 4; ++rg)
#pragma unroll
    for (int qq = 0; qq < 4; ++qq) {
      float m = fmaxf(fmaxf(acc[rg][0][qq], acc[rg][1][qq]),
                      fmaxf(acc[rg][2][qq], acc[rg][3][qq]));
      m = fmaxf(m, __shfl_xor(m, 1));
      m = fmaxf(m, __shfl_xor(m, 2));
      m = fmaxf(m, __shfl_xor(m, 4));
      m = fmaxf(m, __shfl_xor(m, 8));
#pragma unroll
      for (int cg = 0; cg < 4; ++cg)
        acc[rg][cg][qq] = exp2fast(acc[rg][cg][qq] - m);
      float s = acc[rg][0][qq] + acc[rg][1][qq] + acc[rg][2][qq] + acc[rg][3][qq];
      s += __shfl_xor(s, 1);
      s += __shfl_xor(s, 2);
      s += __shfl_xor(s, 4);
      s += __shfl_xor(s, 8);
      if (lr == 0) psq_s[w * 64 + rg * 16 + lk * 4 + qq] = s;  // own-wave segment
    }

  // W_n = max(sw,1e-8)/s_n  (row t of this block; same-wave LDS segment)
  {
    float sv = psq_s[t];
    float muw = fmaxf(sw[(size_t)b * N_ + n0 + t], 1e-8f);
    W_l[t] = muw / sv;
  }

  // iter-1 column partials: T_k = sum_n E_nk * W_n over this block's 256 rows
  float Wv[4][4];
#pragma unroll
  for (int rg = 0; rg < 4; ++rg)
#pragma unroll
    for (int qq = 0; qq < 4; ++qq)
      Wv[rg][qq] = W_l[w * 64 + rg * 16 + lk * 4 + qq];
#pragma unroll
  for (int cg = 0; cg < 4; ++cg) {
    float Tt = 0.f;
#pragma unroll
    for (int rg = 0; rg < 4; ++rg)
#pragma unroll
      for (int qq = 0; qq < 4; ++qq)
        Tt = fmaf(acc[rg][cg][qq], Wv[rg][qq], Tt);
    Tt += __shfl_xor(Tt, 16);
    Tt += __shfl_xor(Tt, 32);
    if (lk == 0) wm_l[w][cg * 16 + lr] = Tt;
  }

  // transpose-stage E (fp16) into LDS scratch (rows padded to 72 halves)
  _Float16* scr = (_Float16*)Bl + (size_t)w * 64 * 72;
#pragma unroll
  for (int rg = 0; rg < 4; ++rg)
#pragma unroll
    for (int cg = 0; cg < 4; ++cg)
#pragma unroll
      for (int qq = 0; qq < 4; ++qq)
        scr[(rg * 16 + lk * 4 + qq) * 72 + cg * 16 + lr] = (_Float16)acc[rg][cg][qq];
  __syncthreads();

  if (t < 64) {
    float T = wm_l[0][t] + wm_l[1][t] + wm_l[2][t] + wm_l[3][t];
    Tp[((size_t)b * 64 + blockIdx.x) * 64 + t] = T;
  }

  // coalesced flush of fp16 E tile
  _Float16* dst = E + ((size_t)b * N_ + n0 + w * 64) * 64;
#pragma unroll
  for (int f = 0; f < 8; ++f) {
    int u = f * 64 + l;
    int row = u >> 3, kq = u & 7;
    half8 v8 = *(const half8*)(scr + row * 72 + kq * 8);
    *(half8*)(dst + row * 64 + kq * 8) = v8;
  }
}

// ---------- persistent iterations 2..20: E staged in LDS ----------
// 1024 blocks (32/batch) x 512 threads x 1 row/thread. Rows 0..487 of each
// block live in LDS (rotate-c swizzle -> conflict-free b128 reads); rows
// 488..511 are re-read from L3 each iteration (24/512 threads, negligible).
// Per-iteration row state is intra-iteration only: nothing the register
// allocator can sink/remat across the barrier (r7-r10 lesson).
__global__ __launch_bounds__(512, 4) void iterp_kernel(
    const _Float16* __restrict__ E, const float* __restrict__ sw,
    const float* __restrict__ Tp64, float* __restrict__ Ta,
    float* __restrict__ Tb, float* __restrict__ W,
    int* __restrict__ bar)
{
  __shared__ __align__(16) unsigned char Elds[EROWS_LDS * 128];  // 62464 B
  __shared__ float wT[8][64];                                    // 2048 B
  __shared__ __align__(16) float V_s[64];                        // 256 B

  const int t = threadIdx.x;
  const int w = t >> 6, l = t & 63;
  const int bid = blockIdx.x;
  const int b = bid >> 5;           // batch
  const int blk = bid & 31;         // block within batch
  const size_t rowg = (size_t)b * N_ + blk * 512 + t;

  const float muw = fmaxf(sw[rowg], 1e-8f);
  const uint4* pE = (const uint4*)(E + rowg * 64);   // 8 x 16B chunks

  // stage this thread's row into LDS, rotate-c swizzle (phys = (c+t)&7)
  if (t < EROWS_LDS) {
#pragma unroll
    for (int c = 0; c < 8; ++c) {
      uint4 v = pE[c];
      *(uint4*)(Elds + t * 128 + (((c + t) & 7) << 4)) = v;
    }
  }

  float Wrun = 0.f;
  int* bcnt = bar + b * 32;   // 128 B apart per batch
  const bool up32 = (l & 32) != 0;
  const bool up16 = (l & 16) != 0;
  const bool up8  = (l & 8)  != 0;
  const bool up4  = (l & 4)  != 0;
  const bool up2  = (l & 2)  != 0;
  const bool up1  = (l & 1)  != 0;

  __syncthreads();   // staging complete

  for (int it = 2; it <= NUM_ITERS_; ++it) {
    // merge previous column partials -> V
    {
      float tp = 0.f;
      if (it == 2) {
        const float* ti = Tp64 + ((size_t)b * 64 + w * 8) * 64 + l;
#pragma unroll
        for (int i = 0; i < 8; ++i) tp += ti[(size_t)i * 64];
      } else {
        const float* ti = ((it & 1) ? Ta : Tb) + ((size_t)b * 32 + w * 4) * 64 + l;
#pragma unroll
        for (int i = 0; i < 4; ++i) tp += ti[(size_t)i * 64];
      }
      wT[w][l] = tp;
    }
    __syncthreads();
    if (t < 64) {
      float s = wT[0][t] + wT[1][t] + wT[2][t] + wT[3][t]
              + wT[4][t] + wT[5][t] + wT[6][t] + wT[7][t];
      V_s[t] = NUW / s;
    }
    __syncthreads();

    // fetch row into intra-iteration locals (LDS swizzled, or global for tail)
    unsigned ew[32];
    if (t < EROWS_LDS) {
#pragma unroll
      for (int c = 0; c < 8; ++c) {
        uint4 v = *(const uint4*)(Elds + t * 128 + (((c + t) & 7) << 4));
        ew[4 * c] = v.x; ew[4 * c + 1] = v.y;
        ew[4 * c + 2] = v.z; ew[4 * c + 3] = v.w;
      }
    } else {
#pragma unroll
      for (int c = 0; c < 8; ++c) {
        uint4 v = pE[c];
        ew[4 * c] = v.x; ew[4 * c + 1] = v.y;
        ew[4 * c + 2] = v.z; ew[4 * c + 3] = v.w;
      }
    }

    // row pass: s = E_row . V
    float s = 0.f;
#pragma unroll
    for (int j = 0; j < 32; ++j) {
      float2 v2 = *(const float2*)&V_s[2 * j];
      s = fmaf(cvt_lo(ew[j]), v2.x, s);
      s = fmaf(cvt_hi(ew[j]), v2.y, s);
    }
    Wrun = muw / s;

    // col pass: products + butterfly transpose-reduce (keep own half, send other)
    float cur[32];
#pragma unroll
    for (int i = 0; i < 16; ++i) {          // level 32 fused with products
      float lo0 = cvt_lo(ew[i]) * Wrun;        // k = 2i
      float lo1 = cvt_hi(ew[i]) * Wrun;        // k = 2i+1
      float hi0 = cvt_lo(ew[16 + i]) * Wrun;   // k = 32+2i
      float hi1 = cvt_hi(ew[16 + i]) * Wrun;   // k = 33+2i
      float k0 = up32 ? hi0 : lo0, sd0 = up32 ? lo0 : hi0;
      float k1 = up32 ? hi1 : lo1, sd1 = up32 ? lo1 : hi1;
      cur[2 * i]     = k0 + __shfl_xor(sd0, 32);
      cur[2 * i + 1] = k1 + __shfl_xor(sd1, 32);
    }
#pragma unroll
    for (int i = 0; i < 16; ++i) {          // level 16
      float a = cur[i], bv = cur[16 + i];
      float kp = up16 ? bv : a, sd = up16 ? a : bv;
      cur[i] = kp + __shfl_xor(sd, 16);
    }
#pragma unroll
    for (int i = 0; i < 8; ++i) {           // level 8
      float a = cur[i], bv = cur[8 + i];
      float kp = up8 ? bv : a, sd = up8 ? a : bv;
      cur[i] = kp + __shfl_xor(sd, 8);
    }
#pragma unroll
    for (int i = 0; i < 4; ++i) {           // level 4
      float a = cur[i], bv = cur[4 + i];
      float kp = up4 ? bv : a, sd = up4 ? a : bv;
      cur[i] = kp + __shfl_xor(sd, 4);
    }
#pragma unroll
    for (int i = 0; i < 2; ++i) {           // level 2
      float a = cur[i], bv = cur[2 + i];
      float kp = up2 ? bv : a, sd = up2 ? a : bv;
      cur[i] = kp + __shfl_xor(sd, 2);
    }
    {                                       // level 1
      float a = cur[0], bv = cur[1];
      float kp = up1 ? bv : a, sd = up1 ? a : bv;
      cur[0] = kp + __shfl_xor(sd, 1);
    }

    wT[w][l] = cur[0];
    __syncthreads();
    if (t < 64) {
      float* Tout = (it & 1) ? Tb : Ta;
      Tout[((size_t)b * 32 + blk) * 64 + t] =
          wT[0][t] + wT[1][t] + wT[2][t] + wT[3][t]
        + wT[4][t] + wT[5][t] + wT[6][t] + wT[7][t];
    }

    // per-batch generation barrier (skip after the last body)
    if (it < NUM_ITERS_) {
      __threadfence();
      __syncthreads();
      if (t == 0) {
        __hip_atomic_fetch_add(bcnt, 1, __ATOMIC_ACQ_REL,
                               __HIP_MEMORY_SCOPE_AGENT);
        const int target = 32 * (it - 1);
        while (__hip_atomic_load(bcnt, __ATOMIC_ACQUIRE,
                                 __HIP_MEMORY_SCOPE_AGENT) < target)
          __builtin_amdgcn_s_sleep(2);
      }
      __syncthreads();
    }
  }
  W[rowg] = Wrun;
}

// ---------- final column merge -> V ----------
__global__ __launch_bounds__(64) void col_merge_kernel(
    const float* __restrict__ Tin, float* __restrict__ Vf)
{
  const int b = blockIdx.x;
  const int k = threadIdx.x;
  float T = 0.f;
#pragma unroll
  for (int j = 0; j < 32; ++j) T += Tin[((size_t)b * 32 + j) * 64 + k];
  Vf[b * 64 + k] = NUW / T;
}

// ---------- finalize: P = W_n * E_nk * V_k ----------
__global__ __launch_bounds__(256) void finalize_kernel(
    const _Float16* __restrict__ E, const float* __restrict__ W,
    const float* __restrict__ Vf, float* __restrict__ out)
{
  const size_t tid = (size_t)blockIdx.x * 256 + threadIdx.x;
  const size_t e0 = tid * 8;
  const int k0 = (int)(e0 & 63);
  const size_t bn = e0 >> 6;
  const int b = (int)(bn >> 14);
  const float Wv = W[bn];
  half8 ev = *(const half8*)(E + e0);
  float4 v0 = *(const float4*)(Vf + b * 64 + k0);
  float4 v1 = *(const float4*)(Vf + b * 64 + k0 + 4);
  float4 o0, o1;
  o0.x = Wv * (float)ev[0] * v0.x;
  o0.y = Wv * (float)ev[1] * v0.y;
  o0.z = Wv * (float)ev[2] * v0.z;
  o0.w = Wv * (float)ev[3] * v0.w;
  o1.x = Wv * (float)ev[4] * v1.x;
  o1.y = Wv * (float)ev[5] * v1.y;
  o1.z = Wv * (float)ev[6] * v1.z;
  o1.w = Wv * (float)ev[7] * v1.w;
  *(float4*)(out + e0) = o0;
  *(float4*)(out + e0 + 4) = o1;
}

extern "C" void kernel_launch(void* const* d_in, const int* in_sizes, int n_in,
                              void* d_out, int out_size, void* d_ws, size_t ws_size,
                              hipStream_t stream)
{
  const float* pix  = (const float*)d_in[0];
  const float* slot = (const float*)d_in[1];
  const float* sw   = (const float*)d_in[2];
  float* out = (float*)d_out;

  char* ws = (char*)d_ws;
  float* W    = (float*)ws;                              // 2 MB
  float* Vf   = (float*)(ws + (2ull << 20));             // 8 KB
  float* ssq  = (float*)(ws + (2ull << 20) + 65536);     // 8 KB
  int*   bar  = (int*)  (ws + (2ull << 20) + 131072);    // 4 KB
  float* TpA  = (float*)(ws + (3ull << 20));             // 512 KB (64 partials/batch)
  float* Ta   = (float*)(ws + (4ull << 20));             // 256 KB (32 partials/batch)
  float* Tb   = (float*)(ws + (5ull << 20));             // 256 KB
  unsigned short* bhi = (unsigned short*)(ws + (6ull << 20));  // 1 MB
  unsigned short* blo = (unsigned short*)(ws + (7ull << 20));  // 1 MB
  _Float16* E = (_Float16*)(ws + (8ull << 20));          // 67 MB

  hipMemsetAsync(bar, 0, 4096, stream);
  slot_prep_kernel<<<B_ * K_, 64, 0, stream>>>(slot, bhi, blo, ssq);
  logk_mfma_kernel<<<dim3(N_ / 256, B_), 256, 0, stream>>>(
      pix, bhi, blo, ssq, sw, E, TpA);
  iterp_kernel<<<dim3(1024), 512, 0, stream>>>(E, sw, TpA, Ta, Tb, W, bar);
  col_merge_kernel<<<B_, 64, 0, stream>>>(Ta, Vf);
  finalize_kernel<<<(unsigned)(((size_t)B_ * N_ * K_ / 8) / 256), 256, 0, stream>>>(
      E, W, Vf, out);
}

// Round 12
// 424.668 us; speedup vs baseline: 8.8340x; 6.7257x over previous
//
#include <hip/hip_runtime.h>
#include <math.h>

#define B_ 32
#define N_ 16384
#define K_ 64
#define D_ 256
#define NUM_ITERS_ 20

#define F2 (20.0f * 1.4426950408889634f)   // (1/eps)*log2(e)
#define CLAMP2 (-144.26950408889634f)      // -100*log2(e)
#define NUW 0.015625f                      // 1/64
#define EROWS_LDS 488

typedef __attribute__((ext_vector_type(8))) short short8;
typedef _Float16 half8 __attribute__((ext_vector_type(8)));
typedef __attribute__((ext_vector_type(4))) float f32x4;

__device__ __forceinline__ float exp2fast(float x) {
#if __has_builtin(__builtin_amdgcn_exp2f)
  return __builtin_amdgcn_exp2f(x);
#else
  return __expf(x * 0.6931471805599453f);
#endif
}

__device__ __forceinline__ unsigned short cvt_bf16_rne(float x) {
  unsigned u = __float_as_uint(x);
  unsigned r = u + 0x7fffu + ((u >> 16) & 1u);
  return (unsigned short)(r >> 16);
}

__device__ __forceinline__ float cvt_lo(unsigned u) {
  unsigned short h = (unsigned short)(u & 0xffffu);
  _Float16 f;
  __builtin_memcpy(&f, &h, 2);
  return (float)f;
}
__device__ __forceinline__ float cvt_hi(unsigned u) {
  unsigned short h = (unsigned short)(u >> 16);
  _Float16 f;
  __builtin_memcpy(&f, &h, 2);
  return (float)f;
}

// relaxed device-coherent accessors (sc0 sc1 path, no cache-walk fences)
__device__ __forceinline__ float agent_ld(const float* p) {
  return __hip_atomic_load(p, __ATOMIC_RELAXED, __HIP_MEMORY_SCOPE_AGENT);
}
__device__ __forceinline__ void agent_st(float* p, float v) {
  __hip_atomic_store(p, v, __ATOMIC_RELAXED, __HIP_MEMORY_SCOPE_AGENT);
}

// ---------- slot prep: fp32 -> bf16 hi/lo planes + exact fp32 ssq ----------
__global__ __launch_bounds__(64) void slot_prep_kernel(
    const float* __restrict__ slot, unsigned short* __restrict__ bhi,
    unsigned short* __restrict__ blo, float* __restrict__ ssq)
{
  const int bk = blockIdx.x;
  const int t  = threadIdx.x;
  const size_t base = (size_t)bk * D_ + t * 4;
  float4 v = *(const float4*)(slot + base);
  float x[4] = {v.x, v.y, v.z, v.w};
  unsigned short h[4], lo[4];
  float sq = 0.f;
#pragma unroll
  for (int i = 0; i < 4; ++i) {
    sq = fmaf(x[i], x[i], sq);
    h[i] = cvt_bf16_rne(x[i]);
    float hf = __uint_as_float((unsigned)h[i] << 16);
    lo[i] = cvt_bf16_rne(x[i] - hf);
  }
  *(ushort4*)(bhi + base) = make_ushort4(h[0], h[1], h[2], h[3]);
  *(ushort4*)(blo + base) = make_ushort4(lo[0], lo[1], lo[2], lo[3]);
#pragma unroll
  for (int off = 32; off >= 1; off >>= 1) sq += __shfl_xor(sq, off);
  if (t == 0) ssq[bk] = sq;
}

// ---------- Phase 1: E = 2^(log2K - rowmax) (fp16) + fused iteration 1 ----------
__global__ __launch_bounds__(256) void logk_mfma_kernel(
    const float* __restrict__ pix, const unsigned short* __restrict__ bhi,
    const unsigned short* __restrict__ blo, const float* __restrict__ ssq,
    const float* __restrict__ sw, _Float16* __restrict__ E,
    float* __restrict__ Tp)
{
  __shared__ unsigned short Bl[2][K_][D_];   // 64 KB; reused as fp16 transpose scratch
  __shared__ float psq_s[256];               // psq, then row sums s
  __shared__ float ssq_s[K_];
  __shared__ float wm_l[4][K_];
  __shared__ float W_l[256];

  const int t  = threadIdx.x;
  const int w  = t >> 6;
  const int l  = t & 63;
  const int lr = l & 15;
  const int lk = l >> 4;
  const int b  = blockIdx.y;
  const int n0 = blockIdx.x * 256;

  {
    const unsigned short* pl0 = bhi + (size_t)b * K_ * D_;
    const unsigned short* pl1 = blo + (size_t)b * K_ * D_;
#pragma unroll
    for (int i = 0; i < 16; ++i) {
      int ci = i * 256 + t;
      int plane = ci >> 11;
      int k = (ci >> 5) & 63;
      int c = (ci & 31) << 4;
      int srcb = c ^ ((k & 7) << 4);
      const unsigned short* sp = (plane ? pl1 : pl0) + (size_t)k * D_ + (srcb >> 1);
      short8 vv = *(const short8*)sp;
      *(short8*)((char*)(&Bl[plane][k][0]) + c) = vv;
    }
    if (t < K_) ssq_s[t] = ssq[b * K_ + t];
  }

  const float* pg = pix + ((size_t)b * N_ + n0 + w * 64 + lr) * D_ + lk * 8;

  f32x4 acc[4][4];
#pragma unroll
  for (int i = 0; i < 4; ++i)
#pragma unroll
    for (int j = 0; j < 4; ++j) acc[i][j] = (f32x4){0.f, 0.f, 0.f, 0.f};
  float psq[4] = {0.f, 0.f, 0.f, 0.f};

  float4 st[4][2];
#pragma unroll
  for (int rg = 0; rg < 4; ++rg) {
    st[rg][0] = *(const float4*)(pg + (size_t)rg * 16 * D_);
    st[rg][1] = *(const float4*)(pg + (size_t)rg * 16 * D_ + 4);
  }
  __syncthreads();

  for (int s = 0; s < 8; ++s) {
    short8 ahi[4], alo[4];
#pragma unroll
    for (int rg = 0; rg < 4; ++rg) {
      float xs[8];
      *(float4*)&xs[0] = st[rg][0];
      *(float4*)&xs[4] = st[rg][1];
#pragma unroll
      for (int j = 0; j < 8; ++j) {
        float x = xs[j];
        psq[rg] = fmaf(x, x, psq[rg]);
        unsigned short h = cvt_bf16_rne(x);
        ahi[rg][j] = (short)h;
        float hf = __uint_as_float((unsigned)h << 16);
        alo[rg][j] = (short)cvt_bf16_rne(x - hf);
      }
    }
    if (s < 7) {
#pragma unroll
      for (int rg = 0; rg < 4; ++rg) {
        st[rg][0] = *(const float4*)(pg + (size_t)rg * 16 * D_ + (s + 1) * 32);
        st[rg][1] = *(const float4*)(pg + (size_t)rg * 16 * D_ + (s + 1) * 32 + 4);
      }
    }
    short8 bh[4], bl[4];
    const int dbyte = s * 64 + lk * 16;
#pragma unroll
    for (int cg = 0; cg < 4; ++cg) {
      int krow = cg * 16 + lr;
      int off = dbyte ^ ((krow & 7) << 4);
      bh[cg] = *(const short8*)((const char*)(&Bl[0][krow][0]) + off);
      bl[cg] = *(const short8*)((const char*)(&Bl[1][krow][0]) + off);
    }
#pragma unroll
    for (int rg = 0; rg < 4; ++rg)
#pragma unroll
      for (int cg = 0; cg < 4; ++cg) {
        acc[rg][cg] = __builtin_amdgcn_mfma_f32_16x16x32_bf16(ahi[rg], bh[cg], acc[rg][cg], 0, 0, 0);
        acc[rg][cg] = __builtin_amdgcn_mfma_f32_16x16x32_bf16(ahi[rg], bl[cg], acc[rg][cg], 0, 0, 0);
        acc[rg][cg] = __builtin_amdgcn_mfma_f32_16x16x32_bf16(alo[rg], bh[cg], acc[rg][cg], 0, 0, 0);
      }
  }

#pragma unroll
  for (int rg = 0; rg < 4; ++rg) {
    psq[rg] += __shfl_xor(psq[rg], 16);
    psq[rg] += __shfl_xor(psq[rg], 32);
  }
  if (l < 16) {
#pragma unroll
    for (int rg = 0; rg < 4; ++rg) psq_s[w * 64 + rg * 16 + lr] = psq[rg];
  }
  __syncthreads();   // psq_s ready; all waves done reading Bl (scr reuse safe)

  float mss[4];
#pragma unroll
  for (int cg = 0; cg < 4; ++cg) mss[cg] = ssq_s[cg * 16 + lr];

  // log2_K into acc
#pragma unroll
  for (int rg = 0; rg < 4; ++rg)
#pragma unroll
    for (int qq = 0; qq < 4; ++qq) {
      float ps_ = psq_s[w * 64 + rg * 16 + lk * 4 + qq];
#pragma unroll
      for (int cg = 0; cg < 4; ++cg) {
        float C = ps_ + mss[cg] - 2.f * acc[rg][cg][qq];
        acc[rg][cg][qq] = fmaxf(-F2 * C, CLAMP2);
      }
    }

  // per-row max -> E = 2^(lk - rmax); row sums s (= iter-1 row pass with V=1)
#pragma unroll
  for (int rg = 0; rg < 4; ++rg)
#pragma unroll
    for (int qq = 0; qq < 4; ++qq) {
      float m = fmaxf(fmaxf(acc[rg][0][qq], acc[rg][1][qq]),
                      fmaxf(acc[rg][2][qq], acc[rg][3][qq]));
      m = fmaxf(m, __shfl_xor(m, 1));
      m = fmaxf(m, __shfl_xor(m, 2));
      m = fmaxf(m, __shfl_xor(m, 4));
      m = fmaxf(m, __shfl_xor(m, 8));
#pragma unroll
      for (int cg = 0; cg < 4; ++cg)
        acc[rg][cg][qq] = exp2fast(acc[rg][cg][qq] - m);
      float s = acc[rg][0][qq] + acc[rg][1][qq] + acc[rg][2][qq] + acc[rg][3][qq];
      s += __shfl_xor(s, 1);
      s += __shfl_xor(s, 2);
      s += __shfl_xor(s, 4);
      s += __shfl_xor(s, 8);
      if (lr == 0) psq_s[w * 64 + rg * 16 + lk * 4 + qq] = s;  // own-wave segment
    }

  // W_n = max(sw,1e-8)/s_n  (row t of this block; same-wave LDS segment)
  {
    float sv = psq_s[t];
    float muw = fmaxf(sw[(size_t)b * N_ + n0 + t], 1e-8f);
    W_l[t] = muw / sv;
  }

  // iter-1 column partials: T_k = sum_n E_nk * W_n over this block's 256 rows
  float Wv[4][4];
#pragma unroll
  for (int rg = 0; rg < 4; ++rg)
#pragma unroll
    for (int qq = 0; qq < 4; ++qq)
      Wv[rg][qq] = W_l[w * 64 + rg * 16 + lk * 4 + qq];
#pragma unroll
  for (int cg = 0; cg < 4; ++cg) {
    float Tt = 0.f;
#pragma unroll
    for (int rg = 0; rg < 4; ++rg)
#pragma unroll
      for (int qq = 0; qq < 4; ++qq)
        Tt = fmaf(acc[rg][cg][qq], Wv[rg][qq], Tt);
    Tt += __shfl_xor(Tt, 16);
    Tt += __shfl_xor(Tt, 32);
    if (lk == 0) wm_l[w][cg * 16 + lr] = Tt;
  }

  // transpose-stage E (fp16) into LDS scratch (rows padded to 72 halves)
  _Float16* scr = (_Float16*)Bl + (size_t)w * 64 * 72;
#pragma unroll
  for (int rg = 0; rg < 4; ++rg)
#pragma unroll
    for (int cg = 0; cg < 4; ++cg)
#pragma unroll
      for (int qq = 0; qq < 4; ++qq)
        scr[(rg * 16 + lk * 4 + qq) * 72 + cg * 16 + lr] = (_Float16)acc[rg][cg][qq];
  __syncthreads();

  if (t < 64) {
    float T = wm_l[0][t] + wm_l[1][t] + wm_l[2][t] + wm_l[3][t];
    Tp[((size_t)b * 64 + blockIdx.x) * 64 + t] = T;
  }

  // coalesced flush of fp16 E tile
  _Float16* dst = E + ((size_t)b * N_ + n0 + w * 64) * 64;
#pragma unroll
  for (int f = 0; f < 8; ++f) {
    int u = f * 64 + l;
    int row = u >> 3, kq = u & 7;
    half8 v8 = *(const half8*)(scr + row * 72 + kq * 8);
    *(half8*)(dst + row * 64 + kq * 8) = v8;
  }
}

// ---------- persistent iterations 2..20: E staged in LDS ----------
// Barrier protocol is FENCE-FREE (r11 lesson: threadfence/acquire polls emit
// per-XCD L2 writeback/invalidate walks ~70us/iter): cross-block data moves
// via relaxed AGENT-scope atomics (sc0/sc1 write-through, device-coherent),
// counter RMW relaxed, spin polls relaxed. __syncthreads() drains vmcnt
// before the RMW, giving data-before-counter ordering.
__global__ __launch_bounds__(512, 4) void iterp_kernel(
    const _Float16* __restrict__ E, const float* __restrict__ sw,
    float* __restrict__ Tp64, float* __restrict__ Ta,
    float* __restrict__ Tb, float* __restrict__ W,
    int* __restrict__ bar)
{
  __shared__ __align__(16) unsigned char Elds[EROWS_LDS * 128];  // 62464 B
  __shared__ float wT[8][64];                                    // 2048 B
  __shared__ __align__(16) float V_s[64];                        // 256 B

  const int t = threadIdx.x;
  const int w = t >> 6, l = t & 63;
  const int bid = blockIdx.x;
  const int b = bid >> 5;           // batch
  const int blk = bid & 31;         // block within batch
  const size_t rowg = (size_t)b * N_ + blk * 512 + t;

  const float muw = fmaxf(sw[rowg], 1e-8f);
  const uint4* pE = (const uint4*)(E + rowg * 64);   // 8 x 16B chunks

  // stage this thread's row into LDS, rotate-c swizzle (phys = (c+t)&7)
  if (t < EROWS_LDS) {
#pragma unroll
    for (int c = 0; c < 8; ++c) {
      uint4 v = pE[c];
      *(uint4*)(Elds + t * 128 + (((c + t) & 7) << 4)) = v;
    }
  }

  float Wrun = 0.f;
  int* bcnt = bar + b * 32;   // 128 B apart per batch
  const bool up32 = (l & 32) != 0;
  const bool up16 = (l & 16) != 0;
  const bool up8  = (l & 8)  != 0;
  const bool up4  = (l & 4)  != 0;
  const bool up2  = (l & 2)  != 0;
  const bool up1  = (l & 1)  != 0;

  __syncthreads();   // staging complete

  for (int it = 2; it <= NUM_ITERS_; ++it) {
    // merge previous column partials -> V (device-coherent relaxed loads)
    {
      float tp = 0.f;
      if (it == 2) {
        const float* ti = Tp64 + ((size_t)b * 64 + w * 8) * 64 + l;
#pragma unroll
        for (int i = 0; i < 8; ++i) tp += agent_ld(ti + (size_t)i * 64);
      } else {
        const float* ti = ((it & 1) ? Ta : Tb) + ((size_t)b * 32 + w * 4) * 64 + l;
#pragma unroll
        for (int i = 0; i < 4; ++i) tp += agent_ld(ti + (size_t)i * 64);
      }
      wT[w][l] = tp;
    }
    __syncthreads();
    if (t < 64) {
      float s = wT[0][t] + wT[1][t] + wT[2][t] + wT[3][t]
              + wT[4][t] + wT[5][t] + wT[6][t] + wT[7][t];
      V_s[t] = NUW / s;
    }
    __syncthreads();

    // fetch row into intra-iteration locals (LDS swizzled, or global for tail)
    unsigned ew[32];
    if (t < EROWS_LDS) {
#pragma unroll
      for (int c = 0; c < 8; ++c) {
        uint4 v = *(const uint4*)(Elds + t * 128 + (((c + t) & 7) << 4));
        ew[4 * c] = v.x; ew[4 * c + 1] = v.y;
        ew[4 * c + 2] = v.z; ew[4 * c + 3] = v.w;
      }
    } else {
#pragma unroll
      for (int c = 0; c < 8; ++c) {
        uint4 v = pE[c];
        ew[4 * c] = v.x; ew[4 * c + 1] = v.y;
        ew[4 * c + 2] = v.z; ew[4 * c + 3] = v.w;
      }
    }

    // row pass: s = E_row . V
    float s = 0.f;
#pragma unroll
    for (int j = 0; j < 32; ++j) {
      float2 v2 = *(const float2*)&V_s[2 * j];
      s = fmaf(cvt_lo(ew[j]), v2.x, s);
      s = fmaf(cvt_hi(ew[j]), v2.y, s);
    }
    Wrun = muw / s;

    // col pass: products + butterfly transpose-reduce (keep own half, send other)
    float cur[32];
#pragma unroll
    for (int i = 0; i < 16; ++i) {          // level 32 fused with products
      float lo0 = cvt_lo(ew[i]) * Wrun;        // k = 2i
      float lo1 = cvt_hi(ew[i]) * Wrun;        // k = 2i+1
      float hi0 = cvt_lo(ew[16 + i]) * Wrun;   // k = 32+2i
      float hi1 = cvt_hi(ew[16 + i]) * Wrun;   // k = 33+2i
      float k0 = up32 ? hi0 : lo0, sd0 = up32 ? lo0 : hi0;
      float k1 = up32 ? hi1 : lo1, sd1 = up32 ? lo1 : hi1;
      cur[2 * i]     = k0 + __shfl_xor(sd0, 32);
      cur[2 * i + 1] = k1 + __shfl_xor(sd1, 32);
    }
#pragma unroll
    for (int i = 0; i < 16; ++i) {          // level 16
      float a = cur[i], bv = cur[16 + i];
      float kp = up16 ? bv : a, sd = up16 ? a : bv;
      cur[i] = kp + __shfl_xor(sd, 16);
    }
#pragma unroll
    for (int i = 0; i < 8; ++i) {           // level 8
      float a = cur[i], bv = cur[8 + i];
      float kp = up8 ? bv : a, sd = up8 ? a : bv;
      cur[i] = kp + __shfl_xor(sd, 8);
    }
#pragma unroll
    for (int i = 0; i < 4; ++i) {           // level 4
      float a = cur[i], bv = cur[4 + i];
      float kp = up4 ? bv : a, sd = up4 ? a : bv;
      cur[i] = kp + __shfl_xor(sd, 4);
    }
#pragma unroll
    for (int i = 0; i < 2; ++i) {           // level 2
      float a = cur[i], bv = cur[2 + i];
      float kp = up2 ? bv : a, sd = up2 ? a : bv;
      cur[i] = kp + __shfl_xor(sd, 2);
    }
    {                                       // level 1
      float a = cur[0], bv = cur[1];
      float kp = up1 ? bv : a, sd = up1 ? a : bv;
      cur[0] = kp + __shfl_xor(sd, 1);
    }

    wT[w][l] = cur[0];
    __syncthreads();
    if (t < 64) {
      float* Tout = (it & 1) ? Tb : Ta;
      float v = wT[0][t] + wT[1][t] + wT[2][t] + wT[3][t]
              + wT[4][t] + wT[5][t] + wT[6][t] + wT[7][t];
      agent_st(&Tout[((size_t)b * 32 + blk) * 64 + t], v);
    }

    // per-batch generation barrier, fence-free (skip after the last body)
    if (it < NUM_ITERS_) {
      __syncthreads();   // drains vmcnt: partials are at the coherent point
      if (t == 0) {
        __hip_atomic_fetch_add(bcnt, 1, __ATOMIC_RELAXED,
                               __HIP_MEMORY_SCOPE_AGENT);
        const int target = 32 * (it - 1);
        while (__hip_atomic_load(bcnt, __ATOMIC_RELAXED,
                                 __HIP_MEMORY_SCOPE_AGENT) < target)
          __builtin_amdgcn_s_sleep(2);
      }
      __syncthreads();
    }
  }
  W[rowg] = Wrun;
}

// ---------- final column merge -> V ----------
__global__ __launch_bounds__(64) void col_merge_kernel(
    const float* __restrict__ Tin, float* __restrict__ Vf)
{
  const int b = blockIdx.x;
  const int k = threadIdx.x;
  float T = 0.f;
#pragma unroll
  for (int j = 0; j < 32; ++j) T += Tin[((size_t)b * 32 + j) * 64 + k];
  Vf[b * 64 + k] = NUW / T;
}

// ---------- finalize: P = W_n * E_nk * V_k ----------
__global__ __launch_bounds__(256) void finalize_kernel(
    const _Float16* __restrict__ E, const float* __restrict__ W,
    const float* __restrict__ Vf, float* __restrict__ out)
{
  const size_t tid = (size_t)blockIdx.x * 256 + threadIdx.x;
  const size_t e0 = tid * 8;
  const int k0 = (int)(e0 & 63);
  const size_t bn = e0 >> 6;
  const int b = (int)(bn >> 14);
  const float Wv = W[bn];
  half8 ev = *(const half8*)(E + e0);
  float4 v0 = *(const float4*)(Vf + b * 64 + k0);
  float4 v1 = *(const float4*)(Vf + b * 64 + k0 + 4);
  float4 o0, o1;
  o0.x = Wv * (float)ev[0] * v0.x;
  o0.y = Wv * (float)ev[1] * v0.y;
  o0.z = Wv * (float)ev[2] * v0.z;
  o0.w = Wv * (float)ev[3] * v0.w;
  o1.x = Wv * (float)ev[4] * v1.x;
  o1.y = Wv * (float)ev[5] * v1.y;
  o1.z = Wv * (float)ev[6] * v1.z;
  o1.w = Wv * (float)ev[7] * v1.w;
  *(float4*)(out + e0) = o0;
  *(float4*)(out + e0 + 4) = o1;
}

extern "C" void kernel_launch(void* const* d_in, const int* in_sizes, int n_in,
                              void* d_out, int out_size, void* d_ws, size_t ws_size,
                              hipStream_t stream)
{
  const float* pix  = (const float*)d_in[0];
  const float* slot = (const float*)d_in[1];
  const float* sw   = (const float*)d_in[2];
  float* out = (float*)d_out;

  char* ws = (char*)d_ws;
  float* W    = (float*)ws;                              // 2 MB
  float* Vf   = (float*)(ws + (2ull << 20));             // 8 KB
  float* ssq  = (float*)(ws + (2ull << 20) + 65536);     // 8 KB
  int*   bar  = (int*)  (ws + (2ull << 20) + 131072);    // 4 KB
  float* TpA  = (float*)(ws + (3ull << 20));             // 512 KB (64 partials/batch)
  float* Ta   = (float*)(ws + (4ull << 20));             // 256 KB (32 partials/batch)
  float* Tb   = (float*)(ws + (5ull << 20));             // 256 KB
  unsigned short* bhi = (unsigned short*)(ws + (6ull << 20));  // 1 MB
  unsigned short* blo = (unsigned short*)(ws + (7ull << 20));  // 1 MB
  _Float16* E = (_Float16*)(ws + (8ull << 20));          // 67 MB

  hipMemsetAsync(bar, 0, 4096, stream);
  slot_prep_kernel<<<B_ * K_, 64, 0, stream>>>(slot, bhi, blo, ssq);
  logk_mfma_kernel<<<dim3(N_ / 256, B_), 256, 0, stream>>>(
      pix, bhi, blo, ssq, sw, E, TpA);
  iterp_kernel<<<dim3(1024), 512, 0, stream>>>(E, sw, TpA, Ta, Tb, W, bar);
  col_merge_kernel<<<B_, 64, 0, stream>>>(Ta, Vf);
  finalize_kernel<<<(unsigned)(((size_t)B_ * N_ * K_ / 8) / 256), 256, 0, stream>>>(
      E, W, Vf, out);
}